// Round 2
// baseline (431.340 us; speedup 1.0000x reference)
//
#include <hip/hip_runtime.h>

#define N_NODES 50000
#define N_EDGES 800000
#define NF 128   // node feature dim
#define EH 32    // edge hidden
#define NB 128   // dst buckets for CSR sort
#define BN 391   // nodes per bucket (128*391 = 50048 >= 50000)
#define NCH 256  // edge chunks
#define CE 3125  // edges per chunk (256*3125 = 800000 exactly)

typedef __bf16 bf16x8 __attribute__((ext_vector_type(8)));
typedef float f32x4 __attribute__((ext_vector_type(4)));
typedef unsigned short u16x8 __attribute__((ext_vector_type(8)));
typedef unsigned short ushort_t;
typedef unsigned int uint_t;

__device__ inline ushort_t f2bf(float x) {
  uint_t u = __builtin_bit_cast(uint_t, x);
  return (ushort_t)((u + 0x7fffu + ((u >> 16) & 1u)) >> 16);
}
__device__ inline float blo(uint_t u) { return __builtin_bit_cast(float, u << 16); }
__device__ inline float bhi(uint_t u) { return __builtin_bit_cast(float, u & 0xffff0000u); }

// ---------------- CSR build: two-level bucket sort ----------------
// f1: per-chunk histogram over NB dst-buckets
__global__ __launch_bounds__(256) void f1_hist(const int* __restrict__ edst,
                                               int* __restrict__ ghist) {
  __shared__ int h[NB];
  int t = threadIdx.x, c = blockIdx.x;
  if (t < NB) h[t] = 0;
  __syncthreads();
  int base = c * CE;
  for (int i = t; i < CE; i += 256) atomicAdd(&h[edst[base + i] / BN], 1);
  __syncthreads();
  if (t < NB) ghist[t * NCH + c] = h[t];  // bucket-major
}

// f2: one-block exclusive scan of 128*256 = 32768 bucket-major counts
__global__ __launch_bounds__(1024) void f2_scan(int* __restrict__ g) {
  __shared__ int part[1024];
  int t = threadIdx.x;
  int base = t * 32;
  int loc[32];
  int s = 0;
  #pragma unroll
  for (int i = 0; i < 32; ++i) { loc[i] = g[base + i]; s += loc[i]; }
  part[t] = s;
  __syncthreads();
  for (int off = 1; off < 1024; off <<= 1) {
    int v = (t >= off) ? part[t - off] : 0;
    __syncthreads();
    part[t] += v;
    __syncthreads();
  }
  int run = part[t] - s;
  #pragma unroll
  for (int i = 0; i < 32; ++i) { int c = loc[i]; g[base + i] = run; run += c; }
}

// f3: bin packed (dst<<16|src) edges into bucket-major ebuf
__global__ __launch_bounds__(256) void f3_bin(const int* __restrict__ esrc,
                                              const int* __restrict__ edst,
                                              const int* __restrict__ gofs,
                                              uint_t* __restrict__ ebuf) {
  __shared__ int cur[NB];
  int t = threadIdx.x, c = blockIdx.x;
  if (t < NB) cur[t] = gofs[t * NCH + c];
  __syncthreads();
  int base = c * CE;
  for (int i = t; i < CE; i += 256) {
    int d = edst[base + i];
    int s = esrc[base + i];
    int p = atomicAdd(&cur[d / BN], 1);
    ebuf[p] = ((uint_t)d << 16) | (uint_t)s;
  }
}

// f4: per-bucket fine fill; also emits rowptr (replaces count+scan chain)
__global__ __launch_bounds__(256) void f4_fill(const uint_t* __restrict__ ebuf,
                                               const int* __restrict__ gofs,
                                               int* __restrict__ rowptr,
                                               int* __restrict__ csr_src) {
  __shared__ int cnt[392];
  __shared__ int cur[392];
  int b = blockIdx.x, t = threadIdx.x;
  int bstart = gofs[b * NCH];
  int bend = (b == NB - 1) ? N_EDGES : gofs[(b + 1) * NCH];
  int nbase = b * BN;
  for (int i = t; i < 392; i += 256) cnt[i] = 0;
  __syncthreads();
  for (int i = bstart + t; i < bend; i += 256)
    atomicAdd(&cnt[(ebuf[i] >> 16) - nbase], 1);
  __syncthreads();
  if (t < 64) {  // wave-0 exclusive scan of cnt[0..390]
    int carry = 0;
    for (int base = 0; base < 392; base += 64) {
      int i = base + t;
      int v = (i < 391) ? cnt[i] : 0;
      int x = v;
      #pragma unroll
      for (int off = 1; off < 64; off <<= 1) {
        int y = __shfl_up(x, off, 64);
        if (t >= off) x += y;
      }
      if (i < 392) cur[i] = x - v + carry;
      carry += __shfl(x, 63, 64);
    }
  }
  __syncthreads();
  for (int i = t; i < BN; i += 256) {
    int g = nbase + i;
    if (g < N_NODES) rowptr[g] = bstart + cur[i];
  }
  if (b == NB - 1 && t == 0) rowptr[N_NODES] = N_EDGES;
  __syncthreads();
  for (int i = bstart + t; i < bend; i += 256) {
    uint_t pk = ebuf[i];
    int p = atomicAdd(&cur[(pk >> 16) - nbase], 1);
    csr_src[bstart + p] = (int)(pk & 0xffffu);
  }
}

// ---------------- packed weight-prep + input cast ----------------
__global__ __launch_bounds__(256) void k_prepcast(
    const float* __restrict__ ws1, const float* __restrict__ wn1,
    const float* __restrict__ ws2, const float* __restrict__ wn2,
    const float* __restrict__ ws3, const float* __restrict__ wn3,
    const float* __restrict__ wu1, const float* __restrict__ wv1,
    const float* __restrict__ wu2, const float* __restrict__ wv2,
    ushort_t* __restrict__ wt1, ushort_t* __restrict__ wt2, ushort_t* __restrict__ wt3,
    ushort_t* __restrict__ wp1, ushort_t* __restrict__ wp2,
    const float* __restrict__ x, ushort_t* __restrict__ xb) {
  int blk = blockIdx.x;
  int t = threadIdx.x;
  if (blk < 448) {  // weight prep (114688 items)
    int i = blk * 256 + t;
    if (i < 98304) {
      int l = i >> 15;
      int j = i & 32767;
      int n = j >> 8, k = j & 255;
      const float* s = (l == 0) ? (k < 128 ? ws1 : wn1)
                     : (l == 1) ? (k < 128 ? ws2 : wn2)
                                : (k < 128 ? ws3 : wn3);
      float v = s[(k & 127) * 128 + n];
      ushort_t* d = (l == 0) ? wt1 : (l == 1) ? wt2 : wt3;
      d[n * 256 + k] = f2bf(v);
    } else if (i < 114688) {
      int j = i - 98304;
      int l = j >> 13;
      int m = j & 8191;
      int n = m >> 7, k = m & 127;
      const float* s = (l == 0) ? (n < 32 ? wu1 : wv1) : (n < 32 ? wu2 : wv2);
      float v = s[k * 32 + (n & 31)];
      ushort_t* d = (l == 0) ? wp1 : wp2;
      d[n * 128 + k] = f2bf(v);
    }
  } else {  // input cast: 1600000 float4 groups / 6250 blocks
    int i = (blk - 448) * 256 + t;
    float4 v = ((const float4*)x)[i];
    uint2 p;
    p.x = (uint_t)f2bf(v.x) | ((uint_t)f2bf(v.y) << 16);
    p.y = (uint_t)f2bf(v.z) | ((uint_t)f2bf(v.w) << 16);
    ((uint2*)xb)[i] = p;
  }
}

// ---------------- fused SAGE: gather-mean (LDS) + MFMA + edge projections ----
// Phase G: each wave gather-means 16 nodes' neighbor rows into LDS hs (bf16).
// Phase M: out = act([h | mean_neigh(h)] @ [Ws;Wn] + b); agg half read from LDS.
// Phase P (if wp): overwrite LDS with bf16 h-tile, compute [hu|hv] = h @ wp.
__global__ __launch_bounds__(256) void k_sage_fused(
    const ushort_t* __restrict__ hb,   // [N,128] bf16: both self and gather src
    const int* __restrict__ rowptr, const int* __restrict__ csr_src,
    const ushort_t* __restrict__ wt,  // [128][256] bf16, k-contiguous
    const float* __restrict__ bias,
    ushort_t* __restrict__ out_bf, float* __restrict__ out_f32,
    const ushort_t* __restrict__ wp,  // [64][128] bf16 or nullptr
    ushort_t* __restrict__ hub, ushort_t* __restrict__ hvb,
    int M, int do_relu) {
  __shared__ ushort_t hs[64][136];  // pad 136: rows 272B; reused agg -> h tile
  int tid = threadIdx.x;
  int wave = tid >> 6, lane = tid & 63;
  int l16 = lane & 15, quad = lane >> 4;
  int row0 = blockIdx.x * 64;

  // ---- Phase G: gather-mean 16 nodes per wave into hs[wave*16 + i][:]
  {
    int sub = lane >> 4;   // neighbor slot 0..3
    int l16g = lane & 15;  // 16B chunk within the 256B row
    for (int i = 0; i < 16; ++i) {
      int n = row0 + wave * 16 + i;
      if (n >= M) break;  // uniform per wave
      int beg = rowptr[n], end = rowptr[n + 1];
      float f[8];
      #pragma unroll
      for (int k = 0; k < 8; ++k) f[k] = 0.f;
      int j = beg + sub;
      for (; j + 4 < end; j += 8) {  // 2-deep ILP
        int s0 = csr_src[j];
        int s1 = csr_src[j + 4];
        uint4 a = *(const uint4*)&hb[s0 * NF + l16g * 8];
        uint4 b = *(const uint4*)&hb[s1 * NF + l16g * 8];
        f[0] += blo(a.x) + blo(b.x); f[1] += bhi(a.x) + bhi(b.x);
        f[2] += blo(a.y) + blo(b.y); f[3] += bhi(a.y) + bhi(b.y);
        f[4] += blo(a.z) + blo(b.z); f[5] += bhi(a.z) + bhi(b.z);
        f[6] += blo(a.w) + blo(b.w); f[7] += bhi(a.w) + bhi(b.w);
      }
      if (j < end) {
        int s0 = csr_src[j];
        uint4 a = *(const uint4*)&hb[s0 * NF + l16g * 8];
        f[0] += blo(a.x); f[1] += bhi(a.x);
        f[2] += blo(a.y); f[3] += bhi(a.y);
        f[4] += blo(a.z); f[5] += bhi(a.z);
        f[6] += blo(a.w); f[7] += bhi(a.w);
      }
      #pragma unroll
      for (int k = 0; k < 8; ++k) {
        f[k] += __shfl_xor(f[k], 16, 64);
        f[k] += __shfl_xor(f[k], 32, 64);
      }
      if (sub == 0) {
        int deg = end - beg;
        float inv = deg > 0 ? 1.0f / (float)deg : 0.f;
        u16x8 p;
        #pragma unroll
        for (int k = 0; k < 8; ++k) p[k] = f2bf(f[k] * inv);
        *(u16x8*)&hs[wave * 16 + i][l16g * 8] = p;
      }
    }
  }
  __syncthreads();

  // ---- Phase M: MFMA over K=256 ([self(global) | agg(LDS)])
  int n0 = wave * 32;
  f32x4 acc[4][2];
  #pragma unroll
  for (int a = 0; a < 4; ++a)
    #pragma unroll
    for (int b = 0; b < 2; ++b) acc[a][b] = (f32x4){0.f, 0.f, 0.f, 0.f};

  #pragma unroll
  for (int ks = 0; ks < 8; ++ks) {
    int k0 = ks * 32;
    bf16x8 afr[4];
    #pragma unroll
    for (int mt = 0; mt < 4; ++mt) {
      if (ks < 4) {
        int r = row0 + mt * 16 + l16;
        if (r >= M) r = M - 1;
        afr[mt] = __builtin_bit_cast(bf16x8, *(const u16x8*)&hb[r * NF + k0 + quad * 8]);
      } else {
        afr[mt] = __builtin_bit_cast(bf16x8,
            *(const u16x8*)&hs[mt * 16 + l16][(k0 & 127) + quad * 8]);
      }
    }
    bf16x8 bfr[2];
    #pragma unroll
    for (int nt = 0; nt < 2; ++nt) {
      int n = n0 + nt * 16 + l16;
      bfr[nt] = __builtin_bit_cast(bf16x8, *(const u16x8*)&wt[n * 256 + k0 + quad * 8]);
    }
    #pragma unroll
    for (int mt = 0; mt < 4; ++mt)
      #pragma unroll
      for (int nt = 0; nt < 2; ++nt)
        acc[mt][nt] = __builtin_amdgcn_mfma_f32_16x16x32_bf16(
            afr[mt], bfr[nt], acc[mt][nt], 0, 0, 0);
  }

  if (wp) __syncthreads();  // all waves done reading agg LDS before overwrite

  #pragma unroll
  for (int nt = 0; nt < 2; ++nt) {
    int col = n0 + nt * 16 + l16;
    float bv = bias[col];
    #pragma unroll
    for (int mt = 0; mt < 4; ++mt) {
      #pragma unroll
      for (int reg = 0; reg < 4; ++reg) {
        int lr = mt * 16 + quad * 4 + reg;
        int r = row0 + lr;
        float v = acc[mt][nt][reg] + bv;
        if (do_relu) v = fmaxf(v, 0.f);
        if (r < M) {
          if (out_f32) out_f32[r * NF + col] = v;
          else         out_bf[r * NF + col] = f2bf(v);
        }
        if (wp) hs[lr][col] = f2bf(v);  // rows >= M hold junk; never stored later
      }
    }
  }

  if (wp) {
    __syncthreads();
    int nb2 = wave * 16;
    f32x4 pacc[4];
    #pragma unroll
    for (int a = 0; a < 4; ++a) pacc[a] = (f32x4){0.f, 0.f, 0.f, 0.f};
    #pragma unroll
    for (int ks = 0; ks < 4; ++ks) {
      int k0 = ks * 32;
      bf16x8 bfrp = __builtin_bit_cast(bf16x8,
          *(const u16x8*)&wp[(nb2 + l16) * NF + k0 + quad * 8]);
      #pragma unroll
      for (int mt = 0; mt < 4; ++mt) {
        bf16x8 afr = __builtin_bit_cast(bf16x8,
            *(const u16x8*)&hs[mt * 16 + l16][k0 + quad * 8]);
        pacc[mt] = __builtin_amdgcn_mfma_f32_16x16x32_bf16(afr, bfrp, pacc[mt], 0, 0, 0);
      }
    }
    int col = nb2 + l16;
    #pragma unroll
    for (int mt = 0; mt < 4; ++mt) {
      #pragma unroll
      for (int reg = 0; reg < 4; ++reg) {
        int r = row0 + mt * 16 + quad * 4 + reg;
        if (r < M) {
          ushort_t v = f2bf(pacc[mt][reg]);
          if (col < 32) hub[r * EH + col] = v;
          else          hvb[r * EH + col - 32] = v;
        }
      }
    }
  }
}

// ---------------- edge MLP, cooperative: 4 lanes per edge ----------------
// EFD==4 (layer 1): write eu1 result to compact [E,4] fp32 buffer.
// EFD==8 (layer 2): ef = [edge_feat | eu1]; assemble the FULL 48B out_ef row
//                   ([ef1 | ef2 | eu2]) so every output cache line is fully
//                   written -> no read-modify-write.
template <int EFD>
__global__ __launch_bounds__(256) void k_edge(
    const ushort_t* __restrict__ hub, const ushort_t* __restrict__ hvb,
    const int* __restrict__ src, const int* __restrict__ dst,
    const float* __restrict__ ef1,        // [E,4] edge_feat
    const float* __restrict__ ef2,        // [E,4] eu1 (EFD==8 only)
    const float* __restrict__ we, const float* __restrict__ b,
    const float* __restrict__ w2, const float* __restrict__ b2,
    float* __restrict__ out, int E) {
  __shared__ float swe[EFD][EH];
  __shared__ float sw2t[4][EH];  // transposed: sw2t[k][j] = w2[j][k]
  __shared__ float sb[EH];
  __shared__ float sb2v[4];
  int tid = threadIdx.x;
  for (int i = tid; i < EFD * EH; i += 256) swe[i >> 5][i & 31] = we[i];
  if (tid < EH * 4) sw2t[tid & 3][tid >> 2] = w2[tid];
  if (tid < EH) sb[tid] = b[tid];
  if (tid < 4) sb2v[tid] = b2[tid];
  __syncthreads();
  int gi = blockIdx.x * 256 + tid;
  int e = gi >> 2;
  int q = gi & 3;
  if (e >= E) return;
  int s = src[e], d = dst[e];
  int cb = q * 8;
  uint4 au = *(const uint4*)&hub[s * EH + cb];
  uint4 av = *(const uint4*)&hvb[d * EH + cb];
  float efv[EFD];
  {
    float4 v = *(const float4*)&ef1[(long long)e * 4];
    efv[0] = v.x; efv[1] = v.y; efv[2] = v.z; efv[3] = v.w;
    if constexpr (EFD == 8) {
      float4 v1 = *(const float4*)&ef2[(long long)e * 4];
      efv[4] = v1.x; efv[5] = v1.y; efv[6] = v1.z; efv[7] = v1.w;
    }
  }
  float t[8];
  t[0] = blo(au.x) + blo(av.x) + sb[cb + 0];
  t[1] = bhi(au.x) + bhi(av.x) + sb[cb + 1];
  t[2] = blo(au.y) + blo(av.y) + sb[cb + 2];
  t[3] = bhi(au.y) + bhi(av.y) + sb[cb + 3];
  t[4] = blo(au.z) + blo(av.z) + sb[cb + 4];
  t[5] = bhi(au.z) + bhi(av.z) + sb[cb + 5];
  t[6] = blo(au.w) + blo(av.w) + sb[cb + 6];
  t[7] = bhi(au.w) + bhi(av.w) + sb[cb + 7];
  #pragma unroll
  for (int i = 0; i < EFD; ++i) {
    float efi = efv[i];
    #pragma unroll
    for (int j = 0; j < 8; ++j) t[j] += efi * swe[i][cb + j];
  }
  #pragma unroll
  for (int j = 0; j < 8; ++j) t[j] = fmaxf(t[j], 0.f);
  float o0 = 0.f, o1 = 0.f, o2 = 0.f, o3 = 0.f;
  #pragma unroll
  for (int j = 0; j < 8; ++j) {
    o0 += t[j] * sw2t[0][cb + j];
    o1 += t[j] * sw2t[1][cb + j];
    o2 += t[j] * sw2t[2][cb + j];
    o3 += t[j] * sw2t[3][cb + j];
  }
  #pragma unroll
  for (int m = 2; m; m >>= 1) {
    o0 += __shfl_xor(o0, m, 64);
    o1 += __shfl_xor(o1, m, 64);
    o2 += __shfl_xor(o2, m, 64);
    o3 += __shfl_xor(o3, m, 64);
  }
  if constexpr (EFD == 4) {
    if (q == 0)
      *(float4*)&out[(long long)e * 4] =
          make_float4(o0 + sb2v[0], o1 + sb2v[1], o2 + sb2v[2], o3 + sb2v[3]);
  } else {
    if (q == 0)
      *(float4*)&out[(long long)e * 12 + 8] =
          make_float4(o0 + sb2v[0], o1 + sb2v[1], o2 + sb2v[2], o3 + sb2v[3]);
    if (q == 1)
      *(float4*)&out[(long long)e * 12] =
          make_float4(efv[0], efv[1], efv[2], efv[3]);
    if (q == 2)
      *(float4*)&out[(long long)e * 12 + 4] =
          make_float4(efv[4], efv[5], efv[6], efv[7]);
  }
}

// ---------------- launch ----------------
extern "C" void kernel_launch(void* const* d_in, const int* in_sizes, int n_in,
                              void* d_out, int out_size, void* d_ws, size_t ws_size,
                              hipStream_t stream) {
  const float* inputs    = (const float*)d_in[0];
  const float* edge_feat = (const float*)d_in[1];
  const float* w_self1   = (const float*)d_in[2];
  const float* w_neigh1  = (const float*)d_in[3];
  const float* b_conv1   = (const float*)d_in[4];
  const float* eu1_wu    = (const float*)d_in[5];
  const float* eu1_wv    = (const float*)d_in[6];
  const float* eu1_we    = (const float*)d_in[7];
  const float* eu1_b     = (const float*)d_in[8];
  const float* eu1_w2    = (const float*)d_in[9];
  const float* eu1_b2    = (const float*)d_in[10];
  const float* w_self2   = (const float*)d_in[11];
  const float* w_neigh2  = (const float*)d_in[12];
  const float* b_conv2   = (const float*)d_in[13];
  const float* eu2_wu    = (const float*)d_in[14];
  const float* eu2_wv    = (const float*)d_in[15];
  const float* eu2_we    = (const float*)d_in[16];
  const float* eu2_b     = (const float*)d_in[17];
  const float* eu2_w2    = (const float*)d_in[18];
  const float* eu2_b2    = (const float*)d_in[19];
  const float* w_self3   = (const float*)d_in[20];
  const float* w_neigh3  = (const float*)d_in[21];
  const float* b_conv3   = (const float*)d_in[22];
  const int*   esrc      = (const int*)d_in[23];
  const int*   edst      = (const int*)d_in[24];

  float* out_h  = (float*)d_out;                           // [N,128]
  float* out_ef = (float*)d_out + (long long)N_NODES * NF; // [E,12]

  // workspace: int region then bf16 region
  int* iws     = (int*)d_ws;
  int* gofs    = iws;                 // 32768 (NB*NCH)
  uint_t* ebuf = (uint_t*)(iws + 32768);  // 800000
  int* rowptr  = iws + 832768;        // 50001 (pad 50004) -> ends 882772
  int* csr_src = iws + 882784;        // 800000 -> ends 1682784
  ushort_t* ub = (ushort_t*)(iws + 1682784);  // byte off 6731136, %16==0
  ushort_t* xb   = ub;                        // N*128 = 6.4e6
  ushort_t* hAb  = ub + 6400000;
  ushort_t* hBb  = ub + 12800000;
  ushort_t* wt1  = ub + 25600000;             // 32768 each
  ushort_t* wt2  = ub + 25632768;
  ushort_t* wt3  = ub + 25665536;
  ushort_t* wp1  = ub + 25698304;             // 8192 each
  ushort_t* wp2  = ub + 25706496;
  // hu/hv layer1 alias hBb (hBb not written until L2 sage, after L1 edge done)
  ushort_t* hub1 = hBb;
  ushort_t* hvb1 = hBb + (long long)N_NODES * EH;
  // hu/hv layer2 alias xb (xb dead after L1 sage reads it)
  ushort_t* hub2 = xb;
  ushort_t* hvb2 = xb + (long long)N_NODES * EH;
  // compact eu1 staging [E,4] fp32: lives in out_h region of d_out, which is
  // dead until the final sage-L3 dispatch (k_edge<8> reads it before that).
  float* eu1t = out_h;  // 12.8MB <= 25.6MB region

  const int N = N_NODES, E = N_EDGES;
  int gsage = (N + 63) / 64;  // 782
  int gedge = (E * 4) / 256;  // 12500 exactly

  // ---- weight prep + input cast (packed), CSR bucket sort
  k_prepcast<<<448 + 6250, 256, 0, stream>>>(
      w_self1, w_neigh1, w_self2, w_neigh2, w_self3, w_neigh3,
      eu1_wu, eu1_wv, eu2_wu, eu2_wv,
      wt1, wt2, wt3, wp1, wp2, inputs, xb);
  f1_hist<<<NCH, 256, 0, stream>>>(edst, gofs);
  f2_scan<<<1, 1024, 0, stream>>>(gofs);
  f3_bin<<<NCH, 256, 0, stream>>>(esrc, edst, gofs, ebuf);
  f4_fill<<<NB, 256, 0, stream>>>(ebuf, gofs, rowptr, csr_src);

  // ---- layer 1 (fused gather+sage+proj)
  k_sage_fused<<<gsage, 256, 0, stream>>>(xb, rowptr, csr_src, wt1, b_conv1,
                                          hAb, nullptr, wp1, hub1, hvb1, N, 1);
  k_edge<4><<<gedge, 256, 0, stream>>>(
      hub1, hvb1, esrc, edst, edge_feat, nullptr, eu1_we, eu1_b, eu1_w2, eu1_b2,
      eu1t, E);

  // ---- layer 2
  k_sage_fused<<<gsage, 256, 0, stream>>>(hAb, rowptr, csr_src, wt2, b_conv2,
                                          hBb, nullptr, wp2, hub2, hvb2, N, 1);
  k_edge<8><<<gedge, 256, 0, stream>>>(
      hub2, hvb2, esrc, edst, edge_feat, eu1t, eu2_we, eu2_b, eu2_w2, eu2_b2,
      out_ef, E);

  // ---- layer 3 (no relu, fp32 output, no proj) -- overwrites eu1t region
  k_sage_fused<<<gsage, 256, 0, stream>>>(hBb, rowptr, csr_src, wt3, b_conv3,
                                          nullptr, out_h, nullptr, nullptr,
                                          nullptr, N, 0);
}

// Round 3
// 384.568 us; speedup vs baseline: 1.1216x; 1.1216x over previous
//
#include <hip/hip_runtime.h>

#define N_NODES 50000
#define N_EDGES 800000
#define NF 128   // node feature dim
#define EH 32    // edge hidden
#define NB 128   // dst buckets for CSR sort
#define BN 391   // nodes per bucket (128*391 = 50048 >= 50000)
#define NCH 256  // edge chunks
#define CE 3125  // edges per chunk (256*3125 = 800000 exactly)

typedef __bf16 bf16x8 __attribute__((ext_vector_type(8)));
typedef float f32x4 __attribute__((ext_vector_type(4)));
typedef unsigned short u16x8 __attribute__((ext_vector_type(8)));
typedef unsigned short ushort_t;
typedef unsigned int uint_t;

__device__ inline ushort_t f2bf(float x) {
  uint_t u = __builtin_bit_cast(uint_t, x);
  return (ushort_t)((u + 0x7fffu + ((u >> 16) & 1u)) >> 16);
}
__device__ inline float blo(uint_t u) { return __builtin_bit_cast(float, u << 16); }
__device__ inline float bhi(uint_t u) { return __builtin_bit_cast(float, u & 0xffff0000u); }

// ---------------- CSR build: two-level bucket sort ----------------
// f1: per-chunk histogram over NB dst-buckets
__global__ __launch_bounds__(256) void f1_hist(const int* __restrict__ edst,
                                               int* __restrict__ ghist) {
  __shared__ int h[NB];
  int t = threadIdx.x, c = blockIdx.x;
  if (t < NB) h[t] = 0;
  __syncthreads();
  int base = c * CE;
  for (int i = t; i < CE; i += 256) atomicAdd(&h[edst[base + i] / BN], 1);
  __syncthreads();
  if (t < NB) ghist[t * NCH + c] = h[t];  // bucket-major
}

// f2: one-block exclusive scan of 128*256 = 32768 bucket-major counts
__global__ __launch_bounds__(1024) void f2_scan(int* __restrict__ g) {
  __shared__ int part[1024];
  int t = threadIdx.x;
  int base = t * 32;
  int loc[32];
  int s = 0;
  #pragma unroll
  for (int i = 0; i < 32; ++i) { loc[i] = g[base + i]; s += loc[i]; }
  part[t] = s;
  __syncthreads();
  for (int off = 1; off < 1024; off <<= 1) {
    int v = (t >= off) ? part[t - off] : 0;
    __syncthreads();
    part[t] += v;
    __syncthreads();
  }
  int run = part[t] - s;
  #pragma unroll
  for (int i = 0; i < 32; ++i) { int c = loc[i]; g[base + i] = run; run += c; }
}

// f3: bin packed (dst<<16|src) edges into bucket-major ebuf
__global__ __launch_bounds__(256) void f3_bin(const int* __restrict__ esrc,
                                              const int* __restrict__ edst,
                                              const int* __restrict__ gofs,
                                              uint_t* __restrict__ ebuf) {
  __shared__ int cur[NB];
  int t = threadIdx.x, c = blockIdx.x;
  if (t < NB) cur[t] = gofs[t * NCH + c];
  __syncthreads();
  int base = c * CE;
  for (int i = t; i < CE; i += 256) {
    int d = edst[base + i];
    int s = esrc[base + i];
    int p = atomicAdd(&cur[d / BN], 1);
    ebuf[p] = ((uint_t)d << 16) | (uint_t)s;
  }
}

// f4: per-bucket fine fill; also emits rowptr (replaces count+scan chain)
__global__ __launch_bounds__(256) void f4_fill(const uint_t* __restrict__ ebuf,
                                               const int* __restrict__ gofs,
                                               int* __restrict__ rowptr,
                                               int* __restrict__ csr_src) {
  __shared__ int cnt[392];
  __shared__ int cur[392];
  int b = blockIdx.x, t = threadIdx.x;
  int bstart = gofs[b * NCH];
  int bend = (b == NB - 1) ? N_EDGES : gofs[(b + 1) * NCH];
  int nbase = b * BN;
  for (int i = t; i < 392; i += 256) cnt[i] = 0;
  __syncthreads();
  for (int i = bstart + t; i < bend; i += 256)
    atomicAdd(&cnt[(ebuf[i] >> 16) - nbase], 1);
  __syncthreads();
  if (t < 64) {  // wave-0 exclusive scan of cnt[0..390]
    int carry = 0;
    for (int base = 0; base < 392; base += 64) {
      int i = base + t;
      int v = (i < 391) ? cnt[i] : 0;
      int x = v;
      #pragma unroll
      for (int off = 1; off < 64; off <<= 1) {
        int y = __shfl_up(x, off, 64);
        if (t >= off) x += y;
      }
      if (i < 392) cur[i] = x - v + carry;
      carry += __shfl(x, 63, 64);
    }
  }
  __syncthreads();
  for (int i = t; i < BN; i += 256) {
    int g = nbase + i;
    if (g < N_NODES) rowptr[g] = bstart + cur[i];
  }
  if (b == NB - 1 && t == 0) rowptr[N_NODES] = N_EDGES;
  __syncthreads();
  for (int i = bstart + t; i < bend; i += 256) {
    uint_t pk = ebuf[i];
    int p = atomicAdd(&cur[(pk >> 16) - nbase], 1);
    csr_src[bstart + p] = (int)(pk & 0xffffu);
  }
}

// ---------------- packed weight-prep + input cast ----------------
__global__ __launch_bounds__(256) void k_prepcast(
    const float* __restrict__ ws1, const float* __restrict__ wn1,
    const float* __restrict__ ws2, const float* __restrict__ wn2,
    const float* __restrict__ ws3, const float* __restrict__ wn3,
    const float* __restrict__ wu1, const float* __restrict__ wv1,
    const float* __restrict__ wu2, const float* __restrict__ wv2,
    ushort_t* __restrict__ wt1, ushort_t* __restrict__ wt2, ushort_t* __restrict__ wt3,
    ushort_t* __restrict__ wp1, ushort_t* __restrict__ wp2,
    const float* __restrict__ x, ushort_t* __restrict__ xb) {
  int blk = blockIdx.x;
  int t = threadIdx.x;
  if (blk < 448) {  // weight prep (114688 items)
    int i = blk * 256 + t;
    if (i < 98304) {
      int l = i >> 15;
      int j = i & 32767;
      int n = j >> 8, k = j & 255;
      const float* s = (l == 0) ? (k < 128 ? ws1 : wn1)
                     : (l == 1) ? (k < 128 ? ws2 : wn2)
                                : (k < 128 ? ws3 : wn3);
      float v = s[(k & 127) * 128 + n];
      ushort_t* d = (l == 0) ? wt1 : (l == 1) ? wt2 : wt3;
      d[n * 256 + k] = f2bf(v);
    } else if (i < 114688) {
      int j = i - 98304;
      int l = j >> 13;
      int m = j & 8191;
      int n = m >> 7, k = m & 127;
      const float* s = (l == 0) ? (n < 32 ? wu1 : wv1) : (n < 32 ? wu2 : wv2);
      float v = s[k * 32 + (n & 31)];
      ushort_t* d = (l == 0) ? wp1 : wp2;
      d[n * 128 + k] = f2bf(v);
    }
  } else {  // input cast: 1600000 float4 groups / 6250 blocks
    int i = (blk - 448) * 256 + t;
    float4 v = ((const float4*)x)[i];
    uint2 p;
    p.x = (uint_t)f2bf(v.x) | ((uint_t)f2bf(v.y) << 16);
    p.y = (uint_t)f2bf(v.z) | ((uint_t)f2bf(v.w) << 16);
    ((uint2*)xb)[i] = p;
  }
}

// ---------------- fused SAGE: gather-mean (LDS) + MFMA + edge projections ----
// Phase G: 4 nodes concurrently per wave (16 lanes x 16B cover one 256B row);
//          each lane privately accumulates its chunk -> NO cross-lane reduce.
// Phase M: out = act([h | mean_neigh(h)] @ [Ws;Wn] + b); agg half read from LDS.
// Phase P (if wp): overwrite LDS with bf16 h-tile, compute [hu|hv] = h @ wp.
__global__ __launch_bounds__(256) void k_sage_fused(
    const ushort_t* __restrict__ hb,   // [N,128] bf16: both self and gather src
    const int* __restrict__ rowptr, const int* __restrict__ csr_src,
    const ushort_t* __restrict__ wt,  // [128][256] bf16, k-contiguous
    const float* __restrict__ bias,
    ushort_t* __restrict__ out_bf, float* __restrict__ out_f32,
    const ushort_t* __restrict__ wp,  // [64][128] bf16 or nullptr
    ushort_t* __restrict__ hub, ushort_t* __restrict__ hvb,
    int M, int do_relu) {
  __shared__ ushort_t hs[64][136];  // pad 136: rows 272B; reused agg -> h tile
  int tid = threadIdx.x;
  int wave = tid >> 6, lane = tid & 63;
  int l16 = lane & 15, quad = lane >> 4;
  int row0 = blockIdx.x * 64;

  // ---- Phase G: 4 rounds x 4 concurrent nodes per wave
  {
    int grp = lane >> 4;   // node slot 0..3
    int l16g = lane & 15;  // 16B chunk within the 256B row
    #pragma unroll
    for (int r = 0; r < 4; ++r) {
      int lr = wave * 16 + r * 4 + grp;  // local row 0..63
      int n = row0 + lr;
      int beg = 0, end = 0;
      if (n < M) { beg = rowptr[n]; end = rowptr[n + 1]; }
      float f[8];
      #pragma unroll
      for (int k = 0; k < 8; ++k) f[k] = 0.f;
      int j = beg;
      for (; j + 4 <= end; j += 4) {  // 4-deep ILP, no cross-lane deps
        int s0 = csr_src[j];
        int s1 = csr_src[j + 1];
        int s2 = csr_src[j + 2];
        int s3 = csr_src[j + 3];
        uint4 a = *(const uint4*)&hb[s0 * NF + l16g * 8];
        uint4 b = *(const uint4*)&hb[s1 * NF + l16g * 8];
        uint4 c = *(const uint4*)&hb[s2 * NF + l16g * 8];
        uint4 d = *(const uint4*)&hb[s3 * NF + l16g * 8];
        f[0] += blo(a.x) + blo(b.x) + blo(c.x) + blo(d.x);
        f[1] += bhi(a.x) + bhi(b.x) + bhi(c.x) + bhi(d.x);
        f[2] += blo(a.y) + blo(b.y) + blo(c.y) + blo(d.y);
        f[3] += bhi(a.y) + bhi(b.y) + bhi(c.y) + bhi(d.y);
        f[4] += blo(a.z) + blo(b.z) + blo(c.z) + blo(d.z);
        f[5] += bhi(a.z) + bhi(b.z) + bhi(c.z) + bhi(d.z);
        f[6] += blo(a.w) + blo(b.w) + blo(c.w) + blo(d.w);
        f[7] += bhi(a.w) + bhi(b.w) + bhi(c.w) + bhi(d.w);
      }
      for (; j < end; ++j) {
        int s0 = csr_src[j];
        uint4 a = *(const uint4*)&hb[s0 * NF + l16g * 8];
        f[0] += blo(a.x); f[1] += bhi(a.x);
        f[2] += blo(a.y); f[3] += bhi(a.y);
        f[4] += blo(a.z); f[5] += bhi(a.z);
        f[6] += blo(a.w); f[7] += bhi(a.w);
      }
      if (n < M) {
        int deg = end - beg;
        float inv = deg > 0 ? 1.0f / (float)deg : 0.f;
        u16x8 p;
        #pragma unroll
        for (int k = 0; k < 8; ++k) p[k] = f2bf(f[k] * inv);
        *(u16x8*)&hs[lr][l16g * 8] = p;
      }
    }
  }
  __syncthreads();

  // ---- Phase M: MFMA over K=256 ([self(global) | agg(LDS)])
  int n0 = wave * 32;
  f32x4 acc[4][2];
  #pragma unroll
  for (int a = 0; a < 4; ++a)
    #pragma unroll
    for (int b = 0; b < 2; ++b) acc[a][b] = (f32x4){0.f, 0.f, 0.f, 0.f};

  #pragma unroll
  for (int ks = 0; ks < 8; ++ks) {
    int k0 = ks * 32;
    bf16x8 afr[4];
    #pragma unroll
    for (int mt = 0; mt < 4; ++mt) {
      if (ks < 4) {
        int r = row0 + mt * 16 + l16;
        if (r >= M) r = M - 1;
        afr[mt] = __builtin_bit_cast(bf16x8, *(const u16x8*)&hb[r * NF + k0 + quad * 8]);
      } else {
        afr[mt] = __builtin_bit_cast(bf16x8,
            *(const u16x8*)&hs[mt * 16 + l16][(k0 & 127) + quad * 8]);
      }
    }
    bf16x8 bfr[2];
    #pragma unroll
    for (int nt = 0; nt < 2; ++nt) {
      int n = n0 + nt * 16 + l16;
      bfr[nt] = __builtin_bit_cast(bf16x8, *(const u16x8*)&wt[n * 256 + k0 + quad * 8]);
    }
    #pragma unroll
    for (int mt = 0; mt < 4; ++mt)
      #pragma unroll
      for (int nt = 0; nt < 2; ++nt)
        acc[mt][nt] = __builtin_amdgcn_mfma_f32_16x16x32_bf16(
            afr[mt], bfr[nt], acc[mt][nt], 0, 0, 0);
  }

  if (wp) __syncthreads();  // all waves done reading agg LDS before overwrite

  #pragma unroll
  for (int nt = 0; nt < 2; ++nt) {
    int col = n0 + nt * 16 + l16;
    float bv = bias[col];
    #pragma unroll
    for (int mt = 0; mt < 4; ++mt) {
      #pragma unroll
      for (int reg = 0; reg < 4; ++reg) {
        int lr = mt * 16 + quad * 4 + reg;
        int r = row0 + lr;
        float v = acc[mt][nt][reg] + bv;
        if (do_relu) v = fmaxf(v, 0.f);
        if (r < M) {
          if (out_f32) out_f32[r * NF + col] = v;
          else         out_bf[r * NF + col] = f2bf(v);
        }
        if (wp) hs[lr][col] = f2bf(v);  // rows >= M hold junk; never stored later
      }
    }
  }

  if (wp) {
    __syncthreads();
    int nb2 = wave * 16;
    f32x4 pacc[4];
    #pragma unroll
    for (int a = 0; a < 4; ++a) pacc[a] = (f32x4){0.f, 0.f, 0.f, 0.f};
    #pragma unroll
    for (int ks = 0; ks < 4; ++ks) {
      int k0 = ks * 32;
      bf16x8 bfrp = __builtin_bit_cast(bf16x8,
          *(const u16x8*)&wp[(nb2 + l16) * NF + k0 + quad * 8]);
      #pragma unroll
      for (int mt = 0; mt < 4; ++mt) {
        bf16x8 afr = __builtin_bit_cast(bf16x8,
            *(const u16x8*)&hs[mt * 16 + l16][k0 + quad * 8]);
        pacc[mt] = __builtin_amdgcn_mfma_f32_16x16x32_bf16(afr, bfrp, pacc[mt], 0, 0, 0);
      }
    }
    int col = nb2 + l16;
    #pragma unroll
    for (int mt = 0; mt < 4; ++mt) {
      #pragma unroll
      for (int reg = 0; reg < 4; ++reg) {
        int r = row0 + mt * 16 + quad * 4 + reg;
        if (r < M) {
          ushort_t v = f2bf(pacc[mt][reg]);
          if (col < 32) hub[r * EH + col] = v;
          else          hvb[r * EH + col - 32] = v;
        }
      }
    }
  }
}

// ---------------- edge MLP, cooperative: 4 lanes per edge ----------------
// EFD==4 (layer 1): write eu1 result to compact [E,4] fp32 buffer.
// EFD==8 (layer 2): ef = [edge_feat | eu1]; assemble the FULL 48B out_ef row
//                   ([ef1 | ef2 | eu2]) so every output cache line is fully
//                   written -> no read-modify-write.
template <int EFD>
__global__ __launch_bounds__(256) void k_edge(
    const ushort_t* __restrict__ hub, const ushort_t* __restrict__ hvb,
    const int* __restrict__ src, const int* __restrict__ dst,
    const float* __restrict__ ef1,        // [E,4] edge_feat
    const float* __restrict__ ef2,        // [E,4] eu1 (EFD==8 only)
    const float* __restrict__ we, const float* __restrict__ b,
    const float* __restrict__ w2, const float* __restrict__ b2,
    float* __restrict__ out, int E) {
  __shared__ float swe[EFD][EH];
  __shared__ float sw2t[4][EH];  // transposed: sw2t[k][j] = w2[j][k]
  __shared__ float sb[EH];
  __shared__ float sb2v[4];
  int tid = threadIdx.x;
  for (int i = tid; i < EFD * EH; i += 256) swe[i >> 5][i & 31] = we[i];
  if (tid < EH * 4) sw2t[tid & 3][tid >> 2] = w2[tid];
  if (tid < EH) sb[tid] = b[tid];
  if (tid < 4) sb2v[tid] = b2[tid];
  __syncthreads();
  int gi = blockIdx.x * 256 + tid;
  int e = gi >> 2;
  int q = gi & 3;
  if (e >= E) return;
  int s = src[e], d = dst[e];
  int cb = q * 8;
  uint4 au = *(const uint4*)&hub[s * EH + cb];
  uint4 av = *(const uint4*)&hvb[d * EH + cb];
  float efv[EFD];
  {
    float4 v = *(const float4*)&ef1[(long long)e * 4];
    efv[0] = v.x; efv[1] = v.y; efv[2] = v.z; efv[3] = v.w;
    if constexpr (EFD == 8) {
      float4 v1 = *(const float4*)&ef2[(long long)e * 4];
      efv[4] = v1.x; efv[5] = v1.y; efv[6] = v1.z; efv[7] = v1.w;
    }
  }
  float t[8];
  t[0] = blo(au.x) + blo(av.x) + sb[cb + 0];
  t[1] = bhi(au.x) + bhi(av.x) + sb[cb + 1];
  t[2] = blo(au.y) + blo(av.y) + sb[cb + 2];
  t[3] = bhi(au.y) + bhi(av.y) + sb[cb + 3];
  t[4] = blo(au.z) + blo(av.z) + sb[cb + 4];
  t[5] = bhi(au.z) + bhi(av.z) + sb[cb + 5];
  t[6] = blo(au.w) + blo(av.w) + sb[cb + 6];
  t[7] = bhi(au.w) + bhi(av.w) + sb[cb + 7];
  #pragma unroll
  for (int i = 0; i < EFD; ++i) {
    float efi = efv[i];
    #pragma unroll
    for (int j = 0; j < 8; ++j) t[j] += efi * swe[i][cb + j];
  }
  #pragma unroll
  for (int j = 0; j < 8; ++j) t[j] = fmaxf(t[j], 0.f);
  float o0 = 0.f, o1 = 0.f, o2 = 0.f, o3 = 0.f;
  #pragma unroll
  for (int j = 0; j < 8; ++j) {
    o0 += t[j] * sw2t[0][cb + j];
    o1 += t[j] * sw2t[1][cb + j];
    o2 += t[j] * sw2t[2][cb + j];
    o3 += t[j] * sw2t[3][cb + j];
  }
  #pragma unroll
  for (int m = 2; m; m >>= 1) {
    o0 += __shfl_xor(o0, m, 64);
    o1 += __shfl_xor(o1, m, 64);
    o2 += __shfl_xor(o2, m, 64);
    o3 += __shfl_xor(o3, m, 64);
  }
  if constexpr (EFD == 4) {
    if (q == 0)
      *(float4*)&out[(long long)e * 4] =
          make_float4(o0 + sb2v[0], o1 + sb2v[1], o2 + sb2v[2], o3 + sb2v[3]);
  } else {
    if (q == 0)
      *(float4*)&out[(long long)e * 12 + 8] =
          make_float4(o0 + sb2v[0], o1 + sb2v[1], o2 + sb2v[2], o3 + sb2v[3]);
    if (q == 1)
      *(float4*)&out[(long long)e * 12] =
          make_float4(efv[0], efv[1], efv[2], efv[3]);
    if (q == 2)
      *(float4*)&out[(long long)e * 12 + 4] =
          make_float4(efv[4], efv[5], efv[6], efv[7]);
  }
}

// ---------------- launch ----------------
extern "C" void kernel_launch(void* const* d_in, const int* in_sizes, int n_in,
                              void* d_out, int out_size, void* d_ws, size_t ws_size,
                              hipStream_t stream) {
  const float* inputs    = (const float*)d_in[0];
  const float* edge_feat = (const float*)d_in[1];
  const float* w_self1   = (const float*)d_in[2];
  const float* w_neigh1  = (const float*)d_in[3];
  const float* b_conv1   = (const float*)d_in[4];
  const float* eu1_wu    = (const float*)d_in[5];
  const float* eu1_wv    = (const float*)d_in[6];
  const float* eu1_we    = (const float*)d_in[7];
  const float* eu1_b     = (const float*)d_in[8];
  const float* eu1_w2    = (const float*)d_in[9];
  const float* eu1_b2    = (const float*)d_in[10];
  const float* w_self2   = (const float*)d_in[11];
  const float* w_neigh2  = (const float*)d_in[12];
  const float* b_conv2   = (const float*)d_in[13];
  const float* eu2_wu    = (const float*)d_in[14];
  const float* eu2_wv    = (const float*)d_in[15];
  const float* eu2_we    = (const float*)d_in[16];
  const float* eu2_b     = (const float*)d_in[17];
  const float* eu2_w2    = (const float*)d_in[18];
  const float* eu2_b2    = (const float*)d_in[19];
  const float* w_self3   = (const float*)d_in[20];
  const float* w_neigh3  = (const float*)d_in[21];
  const float* b_conv3   = (const float*)d_in[22];
  const int*   esrc      = (const int*)d_in[23];
  const int*   edst      = (const int*)d_in[24];

  float* out_h  = (float*)d_out;                           // [N,128]
  float* out_ef = (float*)d_out + (long long)N_NODES * NF; // [E,12]

  // workspace: int region then bf16 region
  int* iws     = (int*)d_ws;
  int* gofs    = iws;                 // 32768 (NB*NCH)
  uint_t* ebuf = (uint_t*)(iws + 32768);  // 800000
  int* rowptr  = iws + 832768;        // 50001 (pad 50004) -> ends 882772
  int* csr_src = iws + 882784;        // 800000 -> ends 1682784
  ushort_t* ub = (ushort_t*)(iws + 1682784);  // byte off 6731136, %16==0
  ushort_t* xb   = ub;                        // N*128 = 6.4e6
  ushort_t* hAb  = ub + 6400000;
  ushort_t* hBb  = ub + 12800000;
  ushort_t* wt1  = ub + 25600000;             // 32768 each
  ushort_t* wt2  = ub + 25632768;
  ushort_t* wt3  = ub + 25665536;
  ushort_t* wp1  = ub + 25698304;             // 8192 each
  ushort_t* wp2  = ub + 25706496;
  // hu/hv layer1 alias hBb (hBb not written until L2 sage, after L1 edge done)
  ushort_t* hub1 = hBb;
  ushort_t* hvb1 = hBb + (long long)N_NODES * EH;
  // hu/hv layer2 alias xb (xb dead after L1 sage reads it)
  ushort_t* hub2 = xb;
  ushort_t* hvb2 = xb + (long long)N_NODES * EH;
  // compact eu1 staging [E,4] fp32: lives in out_h region of d_out, which is
  // dead until the final sage-L3 dispatch (k_edge<8> reads it before that).
  float* eu1t = out_h;  // 12.8MB <= 25.6MB region

  const int N = N_NODES, E = N_EDGES;
  int gsage = (N + 63) / 64;  // 782
  int gedge = (E * 4) / 256;  // 12500 exactly

  // ---- weight prep + input cast (packed), CSR bucket sort
  k_prepcast<<<448 + 6250, 256, 0, stream>>>(
      w_self1, w_neigh1, w_self2, w_neigh2, w_self3, w_neigh3,
      eu1_wu, eu1_wv, eu2_wu, eu2_wv,
      wt1, wt2, wt3, wp1, wp2, inputs, xb);
  f1_hist<<<NCH, 256, 0, stream>>>(edst, gofs);
  f2_scan<<<1, 1024, 0, stream>>>(gofs);
  f3_bin<<<NCH, 256, 0, stream>>>(esrc, edst, gofs, ebuf);
  f4_fill<<<NB, 256, 0, stream>>>(ebuf, gofs, rowptr, csr_src);

  // ---- layer 1 (fused gather+sage+proj)
  k_sage_fused<<<gsage, 256, 0, stream>>>(xb, rowptr, csr_src, wt1, b_conv1,
                                          hAb, nullptr, wp1, hub1, hvb1, N, 1);
  k_edge<4><<<gedge, 256, 0, stream>>>(
      hub1, hvb1, esrc, edst, edge_feat, nullptr, eu1_we, eu1_b, eu1_w2, eu1_b2,
      eu1t, E);

  // ---- layer 2
  k_sage_fused<<<gsage, 256, 0, stream>>>(hAb, rowptr, csr_src, wt2, b_conv2,
                                          hBb, nullptr, wp2, hub2, hvb2, N, 1);
  k_edge<8><<<gedge, 256, 0, stream>>>(
      hub2, hvb2, esrc, edst, edge_feat, eu1t, eu2_we, eu2_b, eu2_w2, eu2_b2,
      out_ef, E);

  // ---- layer 3 (no relu, fp32 output, no proj) -- overwrites eu1t region
  k_sage_fused<<<gsage, 256, 0, stream>>>(hBb, rowptr, csr_src, wt3, b_conv3,
                                          nullptr, out_h, nullptr, nullptr,
                                          nullptr, N, 0);
}